// Round 21
// baseline (347.889 us; speedup 1.0000x reference)
//
#include <hip/hip_runtime.h>
#include <hip/hip_fp8.h>

#define NCLS 1000
#define DIM 256
#define GCAP 500
#define NT16 64                    // 64 tiles of 16 cols over 1024 padded cols
#define SCLF 20.609930f            // 1/(0.07*ln2)
#define CP 23.0f
#define CPLN2 15.94238515f         // 23*ln2
#define LN2 0.69314718056f
#define PADC 2.86102294921875e-06f // 24 * 2^-23 (pad-column contribution)

typedef __attribute__((ext_vector_type(4))) float f32x4;
typedef long long i64;
typedef unsigned long long u64;

#if defined(__has_builtin) && __has_builtin(__builtin_amdgcn_cvt_pk_fp8_f32)
#define CVTPK(a, b, old, hi) __builtin_amdgcn_cvt_pk_fp8_f32((a), (b), (old), (hi))
#else
__device__ __forceinline__ unsigned cvtpk_sw(float a, float b, unsigned old, bool hi) {
  unsigned lo8 = __hip_cvt_float_to_fp8(a, __HIP_SATFINITE, __HIP_E4M3);
  unsigned hi8 = __hip_cvt_float_to_fp8(b, __HIP_SATFINITE, __HIP_E4M3);
  unsigned pk = lo8 | (hi8 << 8);
  return hi ? ((old & 0xffffu) | (pk << 16)) : ((old & 0xffff0000u) | pk);
}
#define CVTPK(a, b, old, hi) cvtpk_sw((a), (b), (old), (hi))
#endif

__device__ __forceinline__ float fexp2(float x) {
#if __has_builtin(__builtin_amdgcn_exp2f)
  return __builtin_amdgcn_exp2f(x);
#else
  return exp2f(x);
#endif
}

// ---------------- K0: scatter rows into per-class lists ------------------------
__global__ __launch_bounds__(256) void scatter_kernel(
    const int* __restrict__ sl, const int* __restrict__ tl, int N,
    int* __restrict__ gcnt, int* __restrict__ glist) {
  const int i = blockIdx.x * 256 + threadIdx.x;
  if (i >= 2 * N) return;
  const int side = (i >= N) ? 1 : 0;
  const int r = i - side * N;
  const int c = (side ? tl : sl)[r];
  const int bin = side * NCLS + c;
  const int slot = atomicAdd(gcnt + bin, 1);
  if (slot < GCAP) glist[(size_t)bin * GCAP + slot] = r;
}

// ---------------- K1: per-class gather + mean + normalize ----------------------
// float4 gather, 4-row groups; optionally emits fp8 row copy + per-row scale
// for the src side (consumed by the fast contrast path). tgt side first.
__global__ __launch_bounds__(256) void proto_kernel(
    const float* __restrict__ sf, const float* __restrict__ tf,
    const int* __restrict__ gcnt, const int* __restrict__ glist,
    float* __restrict__ mean_out, float* __restrict__ spn, float* __restrict__ tpn,
    unsigned char* __restrict__ pbf8,
    float* __restrict__ fscale, unsigned char* __restrict__ ffp8) {
  const int bid = blockIdx.x;
  const int side = (bid < NCLS) ? 1 : 0;          // 1 = tgt (processed first)
  const int c = side ? bid : (bid - NCLS);
  const int bin = side * NCLS + c;
  const float* feats = side ? tf : sf;
  const int* list = glist + (size_t)bin * GCAP;
  const int m = min(gcnt[bin], GCAP);
  const int t = threadIdx.x;
  const int q = t >> 6, l = t & 63;               // group q handles rows i%4==q
  const bool wf8 = (ffp8 != nullptr) && (side == 0);
  __shared__ float Sp[4][256];
  __shared__ float s_red[4];

  // per-row side products: fp8 copy (coalesced 256B) + scale
  #define ROWSIDE(v_, ridx_)                                                    \
    if (wf8) {                                                                  \
      float nn = v_.x * v_.x + v_.y * v_.y + v_.z * v_.z + v_.w * v_.w;         \
      _Pragma("unroll")                                                         \
      for (int o = 1; o < 64; o <<= 1) nn += __shfl_xor(nn, o);                 \
      unsigned pk = CVTPK(v_.x, v_.y, 0u, false);                               \
      pk = CVTPK(v_.z, v_.w, pk, true);                                         \
      ((unsigned*)(ffp8 + (size_t)(ridx_) * 256))[l] = pk;                      \
      if (l == 0) fscale[ridx_] = SCLF / fmaxf(sqrtf(nn), 1e-12f);              \
    }

  float4 A[8];
  #pragma unroll
  for (int u = 0; u < 8; u++) A[u] = make_float4(0.f, 0.f, 0.f, 0.f);
  int i = q;
  for (; i + 28 < m; i += 32) {
    #pragma unroll
    for (int u = 0; u < 8; u++) {
      const int r = list[i + 4 * u];
      const float4 v = *(const float4*)(feats + (size_t)r * DIM + l * 4);
      A[u].x += v.x; A[u].y += v.y; A[u].z += v.z; A[u].w += v.w;
      ROWSIDE(v, r);
    }
  }
  for (; i < m; i += 4) {
    const int r = list[i];
    const float4 v = *(const float4*)(feats + (size_t)r * DIM + l * 4);
    A[0].x += v.x; A[0].y += v.y; A[0].z += v.z; A[0].w += v.w;
    ROWSIDE(v, r);
  }
  float4 s4;
  s4.x = ((A[0].x + A[1].x) + (A[2].x + A[3].x)) + ((A[4].x + A[5].x) + (A[6].x + A[7].x));
  s4.y = ((A[0].y + A[1].y) + (A[2].y + A[3].y)) + ((A[4].y + A[5].y) + (A[6].y + A[7].y));
  s4.z = ((A[0].z + A[1].z) + (A[2].z + A[3].z)) + ((A[4].z + A[5].z) + (A[6].z + A[7].z));
  s4.w = ((A[0].w + A[1].w) + (A[2].w + A[3].w)) + ((A[4].w + A[5].w) + (A[6].w + A[7].w));
  *(float4*)&Sp[q][l * 4] = s4;
  __syncthreads();

  const float sum = ((Sp[0][t] + Sp[1][t]) + (Sp[2][t] + Sp[3][t]));
  const float mean = sum / fmaxf((float)m, 1.0f);
  if (!side) mean_out[(size_t)c * DIM + t] = mean;

  float ss = mean * mean;
  #pragma unroll
  for (int o = 1; o < 64; o <<= 1) ss += __shfl_xor(ss, o);
  if ((t & 63) == 0) s_red[t >> 6] = ss;
  __syncthreads();
  const float tot = s_red[0] + s_red[1] + s_red[2] + s_red[3];
  const float innv = 1.0f / fmaxf(sqrtf(tot), 1e-12f);
  const float p = mean * innv;
  (side ? tpn : spn)[(size_t)c * DIM + t] = p;
  if (!side) {
    size_t off = (size_t)(c >> 4) * 4096 + (size_t)(t >> 6) * 1024
               + (size_t)((t >> 3) & 3) * 256 + (size_t)(c & 15) * 16
               + (size_t)((t >> 5) & 1) * 8 + (t & 7);
    unsigned qq = CVTPK(p, p, 0u, false);
    pbf8[off] = (unsigned char)(qq & 0xffu);
  }
}

// ------- K2: FUSED struct (blocks [0,256)) + contrast ---------------------------
// FAST=1: prologue reads proto-emitted fp8 feats + scales (51MB, no LDS).
// FAST=0: exact R19 prologue (fp32 feats via wave-private LDS transpose).
template<int FAST>
__global__ __launch_bounds__(256, 3) void fused_kernel(
    const float* __restrict__ feats, const int* __restrict__ labels,
    const unsigned char* __restrict__ pbf8, float* __restrict__ accp,
    const float* __restrict__ spn, const float* __restrict__ tpn,
    float* __restrict__ out_struct, float* __restrict__ acc,
    const unsigned char* __restrict__ ffp8, const float* __restrict__ fscale,
    int N, int cblocks) {
  __shared__ __align__(16) unsigned char lds_raw[FAST ? 18432 : 34816];
  const int bid = blockIdx.x;
  const int t = threadIdx.x;

  if (bid < 256) {
    // ================= struct path (256 blocks, 64x64 tiles) ==================
    float (*Sa)[68] = (float(*)[68])(lds_raw);
    float (*Sb)[68] = (float(*)[68])(lds_raw + 4352);
    float (*Ta)[68] = (float(*)[68])(lds_raw + 8704);
    float (*Tb)[68] = (float(*)[68])(lds_raw + 13056);
    float* red = (float*)(lds_raw + 17408);
    const int tx = t & 15, ty = t >> 4;
    const int i0 = (bid >> 4) * 64, j0 = (bid & 15) * 64;
    float cs[4][4], cg[4][4];
    #pragma unroll
    for (int a = 0; a < 4; a++)
      #pragma unroll
      for (int b = 0; b < 4; b++) { cs[a][b] = 0.f; cg[a][b] = 0.f; }

    const int srow = t >> 2;
    const int skq = (t & 3) * 4;
    for (int k0 = 0; k0 < DIM; k0 += 16) {
      __syncthreads();
      {
        float4 z = make_float4(0.f, 0.f, 0.f, 0.f);
        int ra = i0 + srow, rb = j0 + srow;
        float4 va = (ra < NCLS) ? *(const float4*)(spn + (size_t)ra * DIM + k0 + skq) : z;
        float4 vb = (rb < NCLS) ? *(const float4*)(spn + (size_t)rb * DIM + k0 + skq) : z;
        float4 wa = (ra < NCLS) ? *(const float4*)(tpn + (size_t)ra * DIM + k0 + skq) : z;
        float4 wb = (rb < NCLS) ? *(const float4*)(tpn + (size_t)rb * DIM + k0 + skq) : z;
        Sa[skq+0][srow]=va.x; Sa[skq+1][srow]=va.y; Sa[skq+2][srow]=va.z; Sa[skq+3][srow]=va.w;
        Sb[skq+0][srow]=vb.x; Sb[skq+1][srow]=vb.y; Sb[skq+2][srow]=vb.z; Sb[skq+3][srow]=vb.w;
        Ta[skq+0][srow]=wa.x; Ta[skq+1][srow]=wa.y; Ta[skq+2][srow]=wa.z; Ta[skq+3][srow]=wa.w;
        Tb[skq+0][srow]=wb.x; Tb[skq+1][srow]=wb.y; Tb[skq+2][srow]=wb.z; Tb[skq+3][srow]=wb.w;
      }
      __syncthreads();
      #pragma unroll
      for (int k = 0; k < 16; k++) {
        float a[4], b[4], c[4], d[4];
        *(float4*)a = *(const float4*)&Sa[k][ty * 4];
        *(float4*)b = *(const float4*)&Sb[k][tx * 4];
        *(float4*)c = *(const float4*)&Ta[k][ty * 4];
        *(float4*)d = *(const float4*)&Tb[k][tx * 4];
        #pragma unroll
        for (int ii = 0; ii < 4; ii++)
          #pragma unroll
          for (int jj = 0; jj < 4; jj++) {
            cs[ii][jj] = fmaf(a[ii], b[jj], cs[ii][jj]);
            cg[ii][jj] = fmaf(c[ii], d[jj], cg[ii][jj]);
          }
      }
    }
    float d2 = 0.f;
    #pragma unroll
    for (int ii = 0; ii < 4; ii++) {
      int gi = i0 + ty * 4 + ii;
      if (gi < NCLS) {
        #pragma unroll
        for (int jj = 0; jj < 4; jj++) {
          int gj = j0 + tx * 4 + jj;
          if (gj < NCLS) {
            out_struct[(size_t)gi * NCLS + gj] = cs[ii][jj];
            float df = cs[ii][jj] - cg[ii][jj];
            d2 += df * df;
          }
        }
      }
    }
    red[t] = d2;
    __syncthreads();
    for (int o = 128; o > 0; o >>= 1) { if (t < o) red[t] += red[t + o]; __syncthreads(); }
    if (t == 0) atomicAdd(acc, red[0]);
    return;
  }

  // ================= contrast path (no barriers) ==============================
  const int cbid = bid - 256;
  if (cbid >= cblocks) return;
  const int lane = t & 63;
  const int w = t >> 6;
  const int lx = lane & 15, lg = lane >> 4;
  const int row0 = cbid * 128 + w * 32;
  const float4 z4 = make_float4(0.f, 0.f, 0.f, 0.f);
  const unsigned char* bbase = pbf8 + (lg << 8) + (lx << 4);

  i64 af[2][8];            // 32 rows/wave, raw feats in e4m3
  float sclF[2][4];        // (1/(T*ln2))/||f|| per owned row
  float sSt[2][4];
  int lbR[2];              // label of this lane's owned row (per rf)

  if constexpr (FAST) {
    // ---- fast prologue: fp8 feats + scales emitted by proto ----
    #pragma unroll
    for (int rf = 0; rf < 2; rf++) {
      const int r = row0 + rf * 16 + lx;
      const bool v = r < N;
      const int rc = v ? r : (N - 1);
      lbR[rf] = v ? labels[r] : 0;
      const unsigned char* rp8 = ffp8 + (size_t)rc * 256 + (lg << 3);
      #pragma unroll
      for (int kc = 0; kc < 8; kc++)
        af[rf][kc] = v ? *(const i64*)(rp8 + kc * 32) : 0;
      const float sw = v ? fscale[rc] : 0.f;
      #pragma unroll
      for (int reg = 0; reg < 4; reg++) {
        sclF[rf][reg] = __shfl(sw, (lg << 2) | reg);
        sSt[rf][reg] = 0.f;
      }
    }
  } else {
    // ---- R19 prologue: 4 chunks of {stage 32rows x 64cols -> ds_read} ----
    float* Aw = (float*)lds_raw + (size_t)w * (32 * 68);  // wave-private 8.7KB
    float n2a[2] = {0.f, 0.f};
    for (int kc = 0; kc < 4; kc++) {
      #pragma unroll
      for (int i = 0; i < 8; i++) {
        const int f = i * 64 + lane;
        const int row = f >> 4;
        const int c4 = f & 15;
        const int gr = row0 + row;
        float4 v = (gr < N) ? *(const float4*)(feats + (size_t)gr * DIM + kc * 64 + c4 * 4) : z4;
        *(float4*)&Aw[row * 68 + c4 * 4] = v;
      }
      #pragma unroll
      for (int rf = 0; rf < 2; rf++) {
        const int row = rf * 16 + lx;
        #pragma unroll
        for (int kk = 0; kk < 2; kk++) {
          float4 x = *(const float4*)&Aw[row * 68 + kk * 32 + lg * 8];
          float4 y = *(const float4*)&Aw[row * 68 + kk * 32 + lg * 8 + 4];
          n2a[rf] += x.x*x.x + x.y*x.y + x.z*x.z + x.w*x.w
                   + y.x*y.x + y.y*y.y + y.z*y.z + y.w*y.w;
          unsigned w0 = CVTPK(x.x, x.y, 0u, false);
          w0 = CVTPK(x.z, x.w, w0, true);
          unsigned w1 = CVTPK(y.x, y.y, 0u, false);
          w1 = CVTPK(y.z, y.w, w1, true);
          af[rf][kc * 2 + kk] = (i64)(((u64)w1 << 32) | (u64)w0);
        }
      }
    }
    #pragma unroll
    for (int rf = 0; rf < 2; rf++) {
      const int r = row0 + rf * 16 + lx;
      lbR[rf] = (r < N) ? labels[r] : 0;
      float n2 = n2a[rf];
      n2 += __shfl_xor(n2, 16);
      n2 += __shfl_xor(n2, 32);
      const float sw = SCLF / fmaxf(sqrtf(n2), 1e-12f);
      #pragma unroll
      for (int reg = 0; reg < 4; reg++) {
        sclF[rf][reg] = __shfl(sw, (lg << 2) | reg);
        sSt[rf][reg] = 0.f;
      }
    }
  }

  int4 bA[4], bB[4];

  #define LOADB(dst_, cf_)                                                      \
    {                                                                           \
      const int4* gp = (const int4*)(bbase + ((size_t)(cf_) << 12));            \
      _Pragma("unroll")                                                         \
      for (int q = 0; q < 4; q++) dst_[q] = gp[q << 6];                         \
    }

  #define COMPUTE(buf_)                                                         \
    {                                                                           \
      f32x4 d0 = {0.f, 0.f, 0.f, 0.f};                                          \
      f32x4 d1 = {0.f, 0.f, 0.f, 0.f};                                          \
      _Pragma("unroll")                                                         \
      for (int q = 0; q < 4; q++) {                                             \
        i64 e0 = ((const i64*)&buf_[q])[0];                                     \
        i64 e1 = ((const i64*)&buf_[q])[1];                                     \
        d0 = __builtin_amdgcn_mfma_f32_16x16x32_fp8_fp8(af[0][2*q],   e0, d0, 0, 0, 0); \
        d1 = __builtin_amdgcn_mfma_f32_16x16x32_fp8_fp8(af[1][2*q],   e0, d1, 0, 0, 0); \
        d0 = __builtin_amdgcn_mfma_f32_16x16x32_fp8_fp8(af[0][2*q+1], e1, d0, 0, 0, 0); \
        d1 = __builtin_amdgcn_mfma_f32_16x16x32_fp8_fp8(af[1][2*q+1], e1, d1, 0, 0, 0); \
      }                                                                         \
      _Pragma("unroll")                                                         \
      for (int reg = 0; reg < 4; reg++) {                                       \
        sSt[0][reg] += fexp2(fmaf(d0[reg], sclF[0][reg], -CP));                 \
        sSt[1][reg] += fexp2(fmaf(d1[reg], sclF[1][reg], -CP));                 \
      }                                                                         \
    }

  LOADB(bA, 0);
  for (int cf = 0; cf < NT16; cf += 2) {
    LOADB(bB, cf + 1);
    COMPUTE(bA);
    if (cf + 2 < NT16) LOADB(bA, cf + 2);
    COMPUTE(bB);
  }

  // ---- label logits via MFMA diagonal: B-col j = proto of row j's label ----
  float dvalS[2];
  #pragma unroll
  for (int rf = 0; rf < 2; rf++) {
    const int lb = lbR[rf];
    const unsigned char* gB = pbf8 + ((size_t)(lb >> 4) << 12) + (lg << 8)
                            + ((size_t)(lb & 15) << 4);
    f32x4 dL = {0.f, 0.f, 0.f, 0.f};
    #pragma unroll
    for (int q = 0; q < 4; q++) {
      int4 bg = *(const int4*)(gB + (q << 10));
      i64 e0 = ((const i64*)&bg)[0];
      i64 e1 = ((const i64*)&bg)[1];
      dL = __builtin_amdgcn_mfma_f32_16x16x32_fp8_fp8(af[rf][2*q],   e0, dL, 0, 0, 0);
      dL = __builtin_amdgcn_mfma_f32_16x16x32_fp8_fp8(af[rf][2*q+1], e1, dL, 0, 0, 0);
    }
    const int sel = lx & 3;   // diag D[j][j]: at lane ((j>>2)<<4)|j, reg j&3
    dvalS[rf] = (sel == 0) ? dL[0] : (sel == 1) ? dL[1] : (sel == 2) ? dL[2] : dL[3];
  }

  float wl = 0.f;
  #pragma unroll
  for (int rf = 0; rf < 2; rf++)
    #pragma unroll
    for (int reg = 0; reg < 4; reg++) {
      float s = sSt[rf][reg];
      #pragma unroll
      for (int o = 1; o < 16; o <<= 1) s += __shfl_xor(s, o);
      const int j = (lg << 2) + reg;
      const float lbraw = __shfl(dvalS[rf], ((j >> 2) << 4) | j);
      const int row = row0 + rf * 16 + j;
      if (lx == 0 && row < N)
        wl += logf(s - PADC) + CPLN2 - lbraw * sclF[rf][reg] * LN2;
    }

  #pragma unroll
  for (int o = 1; o < 64; o <<= 1) wl += __shfl_xor(wl, o);
  if (lane == 0) atomicAdd(accp + (cbid & 63), wl);
}

// ---------------- K4: scalars ---------------------------------------------------
__global__ void final_kernel(const float* __restrict__ acc,
                             const float* __restrict__ accp,
                             float* __restrict__ out, int N) {
  float c = 0.f;
  for (int i = 0; i < 64; i++) c += accp[i];
  out[0] = acc[0] * (1.0f / (float)(NCLS * NCLS));
  out[1] = c / (float)N;
}

extern "C" void kernel_launch(void* const* d_in, const int* in_sizes, int n_in,
                              void* d_out, int out_size, void* d_ws, size_t ws_size,
                              hipStream_t stream) {
  const float* src_feats  = (const float*)d_in[0];
  const int*   src_labels = (const int*)d_in[1];
  const float* tgt_feats  = (const float*)d_in[2];
  const int*   tgt_labels = (const int*)d_in[3];
  const int N = in_sizes[0] / DIM;

  // ws layout (floats) — zeroed region is contiguous [0, 2080):
  // [0,16)             acc: [0]=struct sq-sum
  // [16,2016)          gcnt: 2000 ints
  // [2016,2080)        accp: 64 contrast partial bins
  // [2080,258080)      src_pn
  // [258080,514080)    tgt_pn
  // [514080,579616)    pbf8: 64 tiles x 4096 bytes (fp8 e4m3)
  // [579616,779616)    fscale: N floats            (fast path only)
  // [779616,+12.8M)    ffp8: N x 256 bytes         (fast path only)
  float* ws = (float*)d_ws;
  float* acc    = ws;
  int*   gcnt   = (int*)(ws + 16);
  float* accp   = ws + 2016;
  float* src_pn = ws + 2080;
  float* tgt_pn = ws + 258080;
  unsigned char* pbf8 = (unsigned char*)(ws + 514080);
  float* fscale = ws + 579616;
  unsigned char* ffp8 = (unsigned char*)(ws + 779616);

  const bool fast = ws_size >= (size_t)56 * 1024 * 1024;

  float* out_f      = (float*)d_out;
  float* out_protos = out_f + 2;
  float* out_struct = out_f + 2 + NCLS * DIM;
  // glist borrows the out_struct region (1M ints); fused struct path overwrites later
  int* glist = (int*)out_struct;

  hipMemsetAsync(ws, 0, 2080 * sizeof(float), stream);        // acc + gcnt + accp
  hipMemsetAsync(pbf8 + 62 * 4096, 0, 2 * 4096, stream);      // pad tiles 62,63

  int sblocks = (2 * N + 255) / 256;
  scatter_kernel<<<sblocks, 256, 0, stream>>>(src_labels, tgt_labels, N, gcnt, glist);

  proto_kernel<<<2 * NCLS, 256, 0, stream>>>(
      src_feats, tgt_feats, gcnt, glist, out_protos, src_pn, tgt_pn, pbf8,
      fast ? fscale : nullptr, fast ? ffp8 : nullptr);

  int cblocks = (N + 127) / 128;
  if (fast) {
    fused_kernel<1><<<256 + cblocks, 256, 0, stream>>>(
        src_feats, src_labels, pbf8, accp, src_pn, tgt_pn, out_struct, acc,
        ffp8, fscale, N, cblocks);
  } else {
    fused_kernel<0><<<256 + cblocks, 256, 0, stream>>>(
        src_feats, src_labels, pbf8, accp, src_pn, tgt_pn, out_struct, acc,
        ffp8, fscale, N, cblocks);
  }

  final_kernel<<<1, 1, 0, stream>>>(acc, accp, out_f, N);
}

// Round 23
// 343.424 us; speedup vs baseline: 1.0130x; 1.0130x over previous
//
#include <hip/hip_runtime.h>
#include <hip/hip_fp8.h>

#define NCLS 1000
#define DIM 256
#define GCAP 500
#define NT16 64                    // 64 tiles of 16 cols over 1024 padded cols
#define SCLF 20.609930f            // 1/(0.07*ln2)
#define CP 23.0f
#define CPLN2 15.94238515f         // 23*ln2
#define LN2 0.69314718056f
#define PADC 2.86102294921875e-06f // 24 * 2^-23 (pad-column contribution)

typedef __attribute__((ext_vector_type(4))) float f32x4;
typedef long long i64;
typedef unsigned long long u64;

#if defined(__has_builtin) && __has_builtin(__builtin_amdgcn_cvt_pk_fp8_f32)
#define CVTPK(a, b, old, hi) __builtin_amdgcn_cvt_pk_fp8_f32((a), (b), (old), (hi))
#else
__device__ __forceinline__ unsigned cvtpk_sw(float a, float b, unsigned old, bool hi) {
  unsigned lo8 = __hip_cvt_float_to_fp8(a, __HIP_SATFINITE, __HIP_E4M3);
  unsigned hi8 = __hip_cvt_float_to_fp8(b, __HIP_SATFINITE, __HIP_E4M3);
  unsigned pk = lo8 | (hi8 << 8);
  return hi ? ((old & 0xffffu) | (pk << 16)) : ((old & 0xffff0000u) | pk);
}
#define CVTPK(a, b, old, hi) cvtpk_sw((a), (b), (old), (hi))
#endif

// fp8 e4m3 -> f32 dequant; sel MUST be a literal constant for the builtin.
#if defined(__has_builtin) && __has_builtin(__builtin_amdgcn_cvt_f32_fp8)
#define CVTF8_C(s_, selc_) __builtin_amdgcn_cvt_f32_fp8((s_), (selc_))
#else
__device__ __forceinline__ float cvtf8_sw(unsigned s, int sel) {
  unsigned b = (s >> (sel * 8)) & 0xffu;
  unsigned sg = (b >> 7) & 1u, e = (b >> 3) & 15u, m = b & 7u;
  float val = (e == 0) ? ldexpf((float)m, -9) : ldexpf((float)(8 + m), (int)e - 10);
  return sg ? -val : val;
}
#define CVTF8_C(s_, selc_) cvtf8_sw((s_), (selc_))
#endif

// sum of squares of the 4 e4m3 bytes in a dword (all sel literals)
__device__ __forceinline__ float fp8x4_sq(unsigned u) {
  const float a0 = CVTF8_C(u, 0);
  const float a1 = CVTF8_C(u, 1);
  const float a2 = CVTF8_C(u, 2);
  const float a3 = CVTF8_C(u, 3);
  return a0 * a0 + a1 * a1 + a2 * a2 + a3 * a3;
}

__device__ __forceinline__ float fexp2(float x) {
#if __has_builtin(__builtin_amdgcn_exp2f)
  return __builtin_amdgcn_exp2f(x);
#else
  return exp2f(x);
#endif
}

// ---------------- K0: scatter rows into per-class lists ------------------------
__global__ __launch_bounds__(256) void scatter_kernel(
    const int* __restrict__ sl, const int* __restrict__ tl, int N,
    int* __restrict__ gcnt, int* __restrict__ glist) {
  const int i = blockIdx.x * 256 + threadIdx.x;
  if (i >= 2 * N) return;
  const int side = (i >= N) ? 1 : 0;
  const int r = i - side * N;
  const int c = (side ? tl : sl)[r];
  const int bin = side * NCLS + c;
  const int slot = atomicAdd(gcnt + bin, 1);
  if (slot < GCAP) glist[(size_t)bin * GCAP + slot] = r;
}

// ---------------- K1: per-class gather + mean + normalize ----------------------
// float4 gather, 4-row groups; src side also emits a coalesced fp8 row copy
// (no norms -- those are computed in the fused prologue from the fp8 data).
__global__ __launch_bounds__(256) void proto_kernel(
    const float* __restrict__ sf, const float* __restrict__ tf,
    const int* __restrict__ gcnt, const int* __restrict__ glist,
    float* __restrict__ mean_out, float* __restrict__ spn, float* __restrict__ tpn,
    unsigned char* __restrict__ pbf8, unsigned char* __restrict__ ffp8) {
  const int bid = blockIdx.x;
  const int side = (bid < NCLS) ? 1 : 0;          // 1 = tgt (processed first)
  const int c = side ? bid : (bid - NCLS);
  const int bin = side * NCLS + c;
  const float* feats = side ? tf : sf;
  const int* list = glist + (size_t)bin * GCAP;
  const int m = min(gcnt[bin], GCAP);
  const int t = threadIdx.x;
  const int q = t >> 6, l = t & 63;               // group q handles rows i%4==q
  const bool wf8 = (ffp8 != nullptr) && (side == 0);
  __shared__ float Sp[4][256];
  __shared__ float s_red[4];

  // per-row side product: fp8 copy, coalesced 256B/row (4B per lane)
  #define ROWSIDE(v_, ridx_)                                                    \
    if (wf8) {                                                                  \
      unsigned pk = CVTPK(v_.x, v_.y, 0u, false);                               \
      pk = CVTPK(v_.z, v_.w, pk, true);                                         \
      ((unsigned*)(ffp8 + (size_t)(ridx_) * 256))[l] = pk;                      \
    }

  float4 A[8];
  #pragma unroll
  for (int u = 0; u < 8; u++) A[u] = make_float4(0.f, 0.f, 0.f, 0.f);
  int i = q;
  for (; i + 28 < m; i += 32) {
    #pragma unroll
    for (int u = 0; u < 8; u++) {
      const int r = list[i + 4 * u];
      const float4 v = *(const float4*)(feats + (size_t)r * DIM + l * 4);
      A[u].x += v.x; A[u].y += v.y; A[u].z += v.z; A[u].w += v.w;
      ROWSIDE(v, r);
    }
  }
  for (; i < m; i += 4) {
    const int r = list[i];
    const float4 v = *(const float4*)(feats + (size_t)r * DIM + l * 4);
    A[0].x += v.x; A[0].y += v.y; A[0].z += v.z; A[0].w += v.w;
    ROWSIDE(v, r);
  }
  float4 s4;
  s4.x = ((A[0].x + A[1].x) + (A[2].x + A[3].x)) + ((A[4].x + A[5].x) + (A[6].x + A[7].x));
  s4.y = ((A[0].y + A[1].y) + (A[2].y + A[3].y)) + ((A[4].y + A[5].y) + (A[6].y + A[7].y));
  s4.z = ((A[0].z + A[1].z) + (A[2].z + A[3].z)) + ((A[4].z + A[5].z) + (A[6].z + A[7].z));
  s4.w = ((A[0].w + A[1].w) + (A[2].w + A[3].w)) + ((A[4].w + A[5].w) + (A[6].w + A[7].w));
  *(float4*)&Sp[q][l * 4] = s4;
  __syncthreads();

  const float sum = ((Sp[0][t] + Sp[1][t]) + (Sp[2][t] + Sp[3][t]));
  const float mean = sum / fmaxf((float)m, 1.0f);
  if (!side) mean_out[(size_t)c * DIM + t] = mean;

  float ss = mean * mean;
  #pragma unroll
  for (int o = 1; o < 64; o <<= 1) ss += __shfl_xor(ss, o);
  if ((t & 63) == 0) s_red[t >> 6] = ss;
  __syncthreads();
  const float tot = s_red[0] + s_red[1] + s_red[2] + s_red[3];
  const float innv = 1.0f / fmaxf(sqrtf(tot), 1e-12f);
  const float p = mean * innv;
  (side ? tpn : spn)[(size_t)c * DIM + t] = p;
  if (!side) {
    size_t off = (size_t)(c >> 4) * 4096 + (size_t)(t >> 6) * 1024
               + (size_t)((t >> 3) & 3) * 256 + (size_t)(c & 15) * 16
               + (size_t)((t >> 5) & 1) * 8 + (t & 7);
    unsigned qq = CVTPK(p, p, 0u, false);
    pbf8[off] = (unsigned char)(qq & 0xffu);
  }
}

// ------- K2: FUSED struct (blocks [0,256)) + contrast ---------------------------
// FAST=1: prologue reads proto-emitted fp8 feats (51MB); norm from fp8 dequant.
// FAST=0: exact R19 prologue (fp32 feats via wave-private LDS transpose).
template<int FAST>
__global__ __launch_bounds__(256, 3) void fused_kernel(
    const float* __restrict__ feats, const int* __restrict__ labels,
    const unsigned char* __restrict__ pbf8, float* __restrict__ accp,
    const float* __restrict__ spn, const float* __restrict__ tpn,
    float* __restrict__ out_struct, float* __restrict__ acc,
    const unsigned char* __restrict__ ffp8,
    int N, int cblocks) {
  __shared__ __align__(16) unsigned char lds_raw[FAST ? 18432 : 34816];
  const int bid = blockIdx.x;
  const int t = threadIdx.x;

  if (bid < 256) {
    // ================= struct path (256 blocks, 64x64 tiles) ==================
    float (*Sa)[68] = (float(*)[68])(lds_raw);
    float (*Sb)[68] = (float(*)[68])(lds_raw + 4352);
    float (*Ta)[68] = (float(*)[68])(lds_raw + 8704);
    float (*Tb)[68] = (float(*)[68])(lds_raw + 13056);
    float* red = (float*)(lds_raw + 17408);
    const int tx = t & 15, ty = t >> 4;
    const int i0 = (bid >> 4) * 64, j0 = (bid & 15) * 64;
    float cs[4][4], cg[4][4];
    #pragma unroll
    for (int a = 0; a < 4; a++)
      #pragma unroll
      for (int b = 0; b < 4; b++) { cs[a][b] = 0.f; cg[a][b] = 0.f; }

    const int srow = t >> 2;
    const int skq = (t & 3) * 4;
    for (int k0 = 0; k0 < DIM; k0 += 16) {
      __syncthreads();
      {
        float4 z = make_float4(0.f, 0.f, 0.f, 0.f);
        int ra = i0 + srow, rb = j0 + srow;
        float4 va = (ra < NCLS) ? *(const float4*)(spn + (size_t)ra * DIM + k0 + skq) : z;
        float4 vb = (rb < NCLS) ? *(const float4*)(spn + (size_t)rb * DIM + k0 + skq) : z;
        float4 wa = (ra < NCLS) ? *(const float4*)(tpn + (size_t)ra * DIM + k0 + skq) : z;
        float4 wb = (rb < NCLS) ? *(const float4*)(tpn + (size_t)rb * DIM + k0 + skq) : z;
        Sa[skq+0][srow]=va.x; Sa[skq+1][srow]=va.y; Sa[skq+2][srow]=va.z; Sa[skq+3][srow]=va.w;
        Sb[skq+0][srow]=vb.x; Sb[skq+1][srow]=vb.y; Sb[skq+2][srow]=vb.z; Sb[skq+3][srow]=vb.w;
        Ta[skq+0][srow]=wa.x; Ta[skq+1][srow]=wa.y; Ta[skq+2][srow]=wa.z; Ta[skq+3][srow]=wa.w;
        Tb[skq+0][srow]=wb.x; Tb[skq+1][srow]=wb.y; Tb[skq+2][srow]=wb.z; Tb[skq+3][srow]=wb.w;
      }
      __syncthreads();
      #pragma unroll
      for (int k = 0; k < 16; k++) {
        float a[4], b[4], c[4], d[4];
        *(float4*)a = *(const float4*)&Sa[k][ty * 4];
        *(float4*)b = *(const float4*)&Sb[k][tx * 4];
        *(float4*)c = *(const float4*)&Ta[k][ty * 4];
        *(float4*)d = *(const float4*)&Tb[k][tx * 4];
        #pragma unroll
        for (int ii = 0; ii < 4; ii++)
          #pragma unroll
          for (int jj = 0; jj < 4; jj++) {
            cs[ii][jj] = fmaf(a[ii], b[jj], cs[ii][jj]);
            cg[ii][jj] = fmaf(c[ii], d[jj], cg[ii][jj]);
          }
      }
    }
    float d2 = 0.f;
    #pragma unroll
    for (int ii = 0; ii < 4; ii++) {
      int gi = i0 + ty * 4 + ii;
      if (gi < NCLS) {
        #pragma unroll
        for (int jj = 0; jj < 4; jj++) {
          int gj = j0 + tx * 4 + jj;
          if (gj < NCLS) {
            out_struct[(size_t)gi * NCLS + gj] = cs[ii][jj];
            float df = cs[ii][jj] - cg[ii][jj];
            d2 += df * df;
          }
        }
      }
    }
    red[t] = d2;
    __syncthreads();
    for (int o = 128; o > 0; o >>= 1) { if (t < o) red[t] += red[t + o]; __syncthreads(); }
    if (t == 0) atomicAdd(acc, red[0]);
    return;
  }

  // ================= contrast path (no barriers) ==============================
  const int cbid = bid - 256;
  if (cbid >= cblocks) return;
  const int lane = t & 63;
  const int w = t >> 6;
  const int lx = lane & 15, lg = lane >> 4;
  const int row0 = cbid * 128 + w * 32;
  const float4 z4 = make_float4(0.f, 0.f, 0.f, 0.f);
  const unsigned char* bbase = pbf8 + (lg << 8) + (lx << 4);

  i64 af[2][8];            // 32 rows/wave, raw feats in e4m3
  float sclF[2][4];        // (1/(T*ln2))/||f|| per owned row
  float sSt[2][4];
  int lbR[2];              // label of this lane's owned row (per rf)

  if constexpr (FAST) {
    // ---- fast prologue: fp8 feats from proto; norm via in-register dequant ----
    #pragma unroll
    for (int rf = 0; rf < 2; rf++) {
      const int r = row0 + rf * 16 + lx;
      const bool v = r < N;
      const int rc = v ? r : (N - 1);
      lbR[rf] = v ? labels[r] : 0;
      const unsigned* rp8 = (const unsigned*)(ffp8 + (size_t)rc * 256) + (lg << 1);
      float n2 = 0.f;
      #pragma unroll
      for (int kc = 0; kc < 8; kc++) {
        const unsigned u0 = v ? rp8[kc * 8]     : 0u;
        const unsigned u1 = v ? rp8[kc * 8 + 1] : 0u;
        af[rf][kc] = (i64)(((u64)u1 << 32) | (u64)u0);
        n2 += fp8x4_sq(u0) + fp8x4_sq(u1);
      }
      n2 += __shfl_xor(n2, 16);
      n2 += __shfl_xor(n2, 32);
      const float sw = SCLF / fmaxf(sqrtf(n2), 1e-12f);
      #pragma unroll
      for (int reg = 0; reg < 4; reg++) {
        sclF[rf][reg] = __shfl(sw, (lg << 2) | reg);
        sSt[rf][reg] = 0.f;
      }
    }
  } else {
    // ---- R19 prologue: 4 chunks of {stage 32rows x 64cols -> ds_read} ----
    float* Aw = (float*)lds_raw + (size_t)w * (32 * 68);  // wave-private 8.7KB
    float n2a[2] = {0.f, 0.f};
    for (int kc = 0; kc < 4; kc++) {
      #pragma unroll
      for (int i = 0; i < 8; i++) {
        const int f = i * 64 + lane;
        const int row = f >> 4;
        const int c4 = f & 15;
        const int gr = row0 + row;
        float4 v = (gr < N) ? *(const float4*)(feats + (size_t)gr * DIM + kc * 64 + c4 * 4) : z4;
        *(float4*)&Aw[row * 68 + c4 * 4] = v;
      }
      #pragma unroll
      for (int rf = 0; rf < 2; rf++) {
        const int row = rf * 16 + lx;
        #pragma unroll
        for (int kk = 0; kk < 2; kk++) {
          float4 x = *(const float4*)&Aw[row * 68 + kk * 32 + lg * 8];
          float4 y = *(const float4*)&Aw[row * 68 + kk * 32 + lg * 8 + 4];
          n2a[rf] += x.x*x.x + x.y*x.y + x.z*x.z + x.w*x.w
                   + y.x*y.x + y.y*y.y + y.z*y.z + y.w*y.w;
          unsigned w0 = CVTPK(x.x, x.y, 0u, false);
          w0 = CVTPK(x.z, x.w, w0, true);
          unsigned w1 = CVTPK(y.x, y.y, 0u, false);
          w1 = CVTPK(y.z, y.w, w1, true);
          af[rf][kc * 2 + kk] = (i64)(((u64)w1 << 32) | (u64)w0);
        }
      }
    }
    #pragma unroll
    for (int rf = 0; rf < 2; rf++) {
      const int r = row0 + rf * 16 + lx;
      lbR[rf] = (r < N) ? labels[r] : 0;
      float n2 = n2a[rf];
      n2 += __shfl_xor(n2, 16);
      n2 += __shfl_xor(n2, 32);
      const float sw = SCLF / fmaxf(sqrtf(n2), 1e-12f);
      #pragma unroll
      for (int reg = 0; reg < 4; reg++) {
        sclF[rf][reg] = __shfl(sw, (lg << 2) | reg);
        sSt[rf][reg] = 0.f;
      }
    }
  }

  int4 bA[4], bB[4];

  #define LOADB(dst_, cf_)                                                      \
    {                                                                           \
      const int4* gp = (const int4*)(bbase + ((size_t)(cf_) << 12));            \
      _Pragma("unroll")                                                         \
      for (int q = 0; q < 4; q++) dst_[q] = gp[q << 6];                         \
    }

  #define COMPUTE(buf_)                                                         \
    {                                                                           \
      f32x4 d0 = {0.f, 0.f, 0.f, 0.f};                                          \
      f32x4 d1 = {0.f, 0.f, 0.f, 0.f};                                          \
      _Pragma("unroll")                                                         \
      for (int q = 0; q < 4; q++) {                                             \
        i64 e0 = ((const i64*)&buf_[q])[0];                                     \
        i64 e1 = ((const i64*)&buf_[q])[1];                                     \
        d0 = __builtin_amdgcn_mfma_f32_16x16x32_fp8_fp8(af[0][2*q],   e0, d0, 0, 0, 0); \
        d1 = __builtin_amdgcn_mfma_f32_16x16x32_fp8_fp8(af[1][2*q],   e0, d1, 0, 0, 0); \
        d0 = __builtin_amdgcn_mfma_f32_16x16x32_fp8_fp8(af[0][2*q+1], e1, d0, 0, 0, 0); \
        d1 = __builtin_amdgcn_mfma_f32_16x16x32_fp8_fp8(af[1][2*q+1], e1, d1, 0, 0, 0); \
      }                                                                         \
      _Pragma("unroll")                                                         \
      for (int reg = 0; reg < 4; reg++) {                                       \
        sSt[0][reg] += fexp2(fmaf(d0[reg], sclF[0][reg], -CP));                 \
        sSt[1][reg] += fexp2(fmaf(d1[reg], sclF[1][reg], -CP));                 \
      }                                                                         \
    }

  LOADB(bA, 0);
  for (int cf = 0; cf < NT16; cf += 2) {
    LOADB(bB, cf + 1);
    COMPUTE(bA);
    if (cf + 2 < NT16) LOADB(bA, cf + 2);
    COMPUTE(bB);
  }

  // ---- label logits via MFMA diagonal: B-col j = proto of row j's label ----
  float dvalS[2];
  #pragma unroll
  for (int rf = 0; rf < 2; rf++) {
    const int lb = lbR[rf];
    const unsigned char* gB = pbf8 + ((size_t)(lb >> 4) << 12) + (lg << 8)
                            + ((size_t)(lb & 15) << 4);
    f32x4 dL = {0.f, 0.f, 0.f, 0.f};
    #pragma unroll
    for (int q = 0; q < 4; q++) {
      int4 bg = *(const int4*)(gB + (q << 10));
      i64 e0 = ((const i64*)&bg)[0];
      i64 e1 = ((const i64*)&bg)[1];
      dL = __builtin_amdgcn_mfma_f32_16x16x32_fp8_fp8(af[rf][2*q],   e0, dL, 0, 0, 0);
      dL = __builtin_amdgcn_mfma_f32_16x16x32_fp8_fp8(af[rf][2*q+1], e1, dL, 0, 0, 0);
    }
    const int sel = lx & 3;   // diag D[j][j]: at lane ((j>>2)<<4)|j, reg j&3
    dvalS[rf] = (sel == 0) ? dL[0] : (sel == 1) ? dL[1] : (sel == 2) ? dL[2] : dL[3];
  }

  float wl = 0.f;
  #pragma unroll
  for (int rf = 0; rf < 2; rf++)
    #pragma unroll
    for (int reg = 0; reg < 4; reg++) {
      float s = sSt[rf][reg];
      #pragma unroll
      for (int o = 1; o < 16; o <<= 1) s += __shfl_xor(s, o);
      const int j = (lg << 2) + reg;
      const float lbraw = __shfl(dvalS[rf], ((j >> 2) << 4) | j);
      const int row = row0 + rf * 16 + j;
      if (lx == 0 && row < N)
        wl += logf(s - PADC) + CPLN2 - lbraw * sclF[rf][reg] * LN2;
    }

  #pragma unroll
  for (int o = 1; o < 64; o <<= 1) wl += __shfl_xor(wl, o);
  if (lane == 0) atomicAdd(accp + (cbid & 63), wl);
}

// ---------------- K4: scalars ---------------------------------------------------
__global__ void final_kernel(const float* __restrict__ acc,
                             const float* __restrict__ accp,
                             float* __restrict__ out, int N) {
  float c = 0.f;
  for (int i = 0; i < 64; i++) c += accp[i];
  out[0] = acc[0] * (1.0f / (float)(NCLS * NCLS));
  out[1] = c / (float)N;
}

extern "C" void kernel_launch(void* const* d_in, const int* in_sizes, int n_in,
                              void* d_out, int out_size, void* d_ws, size_t ws_size,
                              hipStream_t stream) {
  const float* src_feats  = (const float*)d_in[0];
  const int*   src_labels = (const int*)d_in[1];
  const float* tgt_feats  = (const float*)d_in[2];
  const int*   tgt_labels = (const int*)d_in[3];
  const int N = in_sizes[0] / DIM;

  // ws layout (floats) — zeroed region is contiguous [0, 2080):
  // [0,16)             acc: [0]=struct sq-sum
  // [16,2016)          gcnt: 2000 ints
  // [2016,2080)        accp: 64 contrast partial bins
  // [2080,258080)      src_pn
  // [258080,514080)    tgt_pn
  // [514080,579616)    pbf8: 64 tiles x 4096 bytes (fp8 e4m3)
  // [579616,+12.8M)    ffp8: N x 256 bytes         (fast path only)
  float* ws = (float*)d_ws;
  float* acc    = ws;
  int*   gcnt   = (int*)(ws + 16);
  float* accp   = ws + 2016;
  float* src_pn = ws + 2080;
  float* tgt_pn = ws + 258080;
  unsigned char* pbf8 = (unsigned char*)(ws + 514080);
  unsigned char* ffp8 = (unsigned char*)(ws + 579616);

  const bool fast = ws_size >= (size_t)56 * 1024 * 1024;

  float* out_f      = (float*)d_out;
  float* out_protos = out_f + 2;
  float* out_struct = out_f + 2 + NCLS * DIM;
  // glist borrows the out_struct region (1M ints); fused struct path overwrites later
  int* glist = (int*)out_struct;

  hipMemsetAsync(ws, 0, 2080 * sizeof(float), stream);        // acc + gcnt + accp
  hipMemsetAsync(pbf8 + 62 * 4096, 0, 2 * 4096, stream);      // pad tiles 62,63

  int sblocks = (2 * N + 255) / 256;
  scatter_kernel<<<sblocks, 256, 0, stream>>>(src_labels, tgt_labels, N, gcnt, glist);

  proto_kernel<<<2 * NCLS, 256, 0, stream>>>(
      src_feats, tgt_feats, gcnt, glist, out_protos, src_pn, tgt_pn, pbf8,
      fast ? ffp8 : nullptr);

  int cblocks = (N + 127) / 128;
  if (fast) {
    fused_kernel<1><<<256 + cblocks, 256, 0, stream>>>(
        src_feats, src_labels, pbf8, accp, src_pn, tgt_pn, out_struct, acc,
        ffp8, N, cblocks);
  } else {
    fused_kernel<0><<<256 + cblocks, 256, 0, stream>>>(
        src_feats, src_labels, pbf8, accp, src_pn, tgt_pn, out_struct, acc,
        ffp8, N, cblocks);
  }

  final_kernel<<<1, 1, 0, stream>>>(acc, accp, out_f, N);
}

// Round 24
// 313.412 us; speedup vs baseline: 1.1100x; 1.0958x over previous
//
#include <hip/hip_runtime.h>
#include <hip/hip_fp8.h>

#define NCLS 1000
#define DIM 256
#define GCAP 500
#define NT16 64                    // 64 tiles of 16 cols over 1024 padded cols
#define SCLF 20.609930f            // 1/(0.07*ln2)
#define CP 23.0f
#define CPLN2 15.94238515f         // 23*ln2
#define LN2 0.69314718056f
#define PADC 2.86102294921875e-06f // 24 * 2^-23 (pad-column contribution)

typedef __attribute__((ext_vector_type(4))) float f32x4;
typedef long long i64;
typedef unsigned long long u64;

#if defined(__has_builtin) && __has_builtin(__builtin_amdgcn_cvt_pk_fp8_f32)
#define CVTPK(a, b, old, hi) __builtin_amdgcn_cvt_pk_fp8_f32((a), (b), (old), (hi))
#else
__device__ __forceinline__ unsigned cvtpk_sw(float a, float b, unsigned old, bool hi) {
  unsigned lo8 = __hip_cvt_float_to_fp8(a, __HIP_SATFINITE, __HIP_E4M3);
  unsigned hi8 = __hip_cvt_float_to_fp8(b, __HIP_SATFINITE, __HIP_E4M3);
  unsigned pk = lo8 | (hi8 << 8);
  return hi ? ((old & 0xffffu) | (pk << 16)) : ((old & 0xffff0000u) | pk);
}
#define CVTPK(a, b, old, hi) cvtpk_sw((a), (b), (old), (hi))
#endif

__device__ __forceinline__ float fexp2(float x) {
#if __has_builtin(__builtin_amdgcn_exp2f)
  return __builtin_amdgcn_exp2f(x);
#else
  return exp2f(x);
#endif
}

// ---------------- K0: scatter rows into per-class lists ------------------------
__global__ __launch_bounds__(256) void scatter_kernel(
    const int* __restrict__ sl, const int* __restrict__ tl, int N,
    int* __restrict__ gcnt, int* __restrict__ glist) {
  const int i = blockIdx.x * 256 + threadIdx.x;
  if (i >= 2 * N) return;
  const int side = (i >= N) ? 1 : 0;
  const int r = i - side * N;
  const int c = (side ? tl : sl)[r];
  const int bin = side * NCLS + c;
  const int slot = atomicAdd(gcnt + bin, 1);
  if (slot < GCAP) glist[(size_t)bin * GCAP + slot] = r;
}

// ---------------- K1: per-class gather + mean + normalize ----------------------
// float4 gather, 4-row groups (32 rows in flight per block). tgt side first.
__global__ __launch_bounds__(256) void proto_kernel(
    const float* __restrict__ sf, const float* __restrict__ tf,
    const int* __restrict__ gcnt, const int* __restrict__ glist,
    float* __restrict__ mean_out, float* __restrict__ spn, float* __restrict__ tpn,
    unsigned char* __restrict__ pbf8) {
  const int bid = blockIdx.x;
  const int side = (bid < NCLS) ? 1 : 0;          // 1 = tgt (processed first)
  const int c = side ? bid : (bid - NCLS);
  const int bin = side * NCLS + c;
  const float* feats = side ? tf : sf;
  const int* list = glist + (size_t)bin * GCAP;
  const int m = min(gcnt[bin], GCAP);
  const int t = threadIdx.x;
  const int q = t >> 6, l = t & 63;               // group q handles rows i%4==q
  __shared__ float Sp[4][256];
  __shared__ float s_red[4];

  float4 A[8];
  #pragma unroll
  for (int u = 0; u < 8; u++) A[u] = make_float4(0.f, 0.f, 0.f, 0.f);
  int i = q;
  for (; i + 28 < m; i += 32) {
    #pragma unroll
    for (int u = 0; u < 8; u++) {
      const float4 v = *(const float4*)(feats + (size_t)list[i + 4 * u] * DIM + l * 4);
      A[u].x += v.x; A[u].y += v.y; A[u].z += v.z; A[u].w += v.w;
    }
  }
  for (; i < m; i += 4) {
    const float4 v = *(const float4*)(feats + (size_t)list[i] * DIM + l * 4);
    A[0].x += v.x; A[0].y += v.y; A[0].z += v.z; A[0].w += v.w;
  }
  float4 s4;
  s4.x = ((A[0].x + A[1].x) + (A[2].x + A[3].x)) + ((A[4].x + A[5].x) + (A[6].x + A[7].x));
  s4.y = ((A[0].y + A[1].y) + (A[2].y + A[3].y)) + ((A[4].y + A[5].y) + (A[6].y + A[7].y));
  s4.z = ((A[0].z + A[1].z) + (A[2].z + A[3].z)) + ((A[4].z + A[5].z) + (A[6].z + A[7].z));
  s4.w = ((A[0].w + A[1].w) + (A[2].w + A[3].w)) + ((A[4].w + A[5].w) + (A[6].w + A[7].w));
  *(float4*)&Sp[q][l * 4] = s4;
  __syncthreads();

  const float sum = ((Sp[0][t] + Sp[1][t]) + (Sp[2][t] + Sp[3][t]));
  const float mean = sum / fmaxf((float)m, 1.0f);
  if (!side) mean_out[(size_t)c * DIM + t] = mean;

  float ss = mean * mean;
  #pragma unroll
  for (int o = 1; o < 64; o <<= 1) ss += __shfl_xor(ss, o);
  if ((t & 63) == 0) s_red[t >> 6] = ss;
  __syncthreads();
  const float tot = s_red[0] + s_red[1] + s_red[2] + s_red[3];
  const float innv = 1.0f / fmaxf(sqrtf(tot), 1e-12f);
  const float p = mean * innv;
  (side ? tpn : spn)[(size_t)c * DIM + t] = p;
  if (!side) {
    size_t off = (size_t)(c >> 4) * 4096 + (size_t)(t >> 6) * 1024
               + (size_t)((t >> 3) & 3) * 256 + (size_t)(c & 15) * 16
               + (size_t)((t >> 5) & 1) * 8 + (t & 7);
    unsigned qq = CVTPK(p, p, 0u, false);
    pbf8[off] = (unsigned char)(qq & 0xffu);
  }
}

// ------- K2: FUSED struct (blocks [0,256)) + contrast (R19 structure + T5) -----
__global__ __launch_bounds__(256, 3) void fused_kernel(
    const float* __restrict__ feats, const int* __restrict__ labels,
    const unsigned char* __restrict__ pbf8, float* __restrict__ accp,
    const float* __restrict__ spn, const float* __restrict__ tpn,
    float* __restrict__ out_struct, float* __restrict__ acc,
    int N, int cblocks) {
  // shared raw buffer, aliased by both paths:
  //  struct path: Sa/Sb/Ta/Tb (4x16x68 f32) + red (256 f32) = 18432 B
  //  contrast path: per-wave A-stage, 4 waves x 32x68 f32 = 34816 B
  __shared__ __align__(16) unsigned char lds_raw[34816];
  const int bid = blockIdx.x;
  const int t = threadIdx.x;

  if (bid < 256) {
    // ================= struct path (256 blocks, 64x64 tiles) ==================
    float (*Sa)[68] = (float(*)[68])(lds_raw);
    float (*Sb)[68] = (float(*)[68])(lds_raw + 4352);
    float (*Ta)[68] = (float(*)[68])(lds_raw + 8704);
    float (*Tb)[68] = (float(*)[68])(lds_raw + 13056);
    float* red = (float*)(lds_raw + 17408);
    const int tx = t & 15, ty = t >> 4;
    const int i0 = (bid >> 4) * 64, j0 = (bid & 15) * 64;
    float cs[4][4], cg[4][4];
    #pragma unroll
    for (int a = 0; a < 4; a++)
      #pragma unroll
      for (int b = 0; b < 4; b++) { cs[a][b] = 0.f; cg[a][b] = 0.f; }

    const int srow = t >> 2;
    const int skq = (t & 3) * 4;
    for (int k0 = 0; k0 < DIM; k0 += 16) {
      __syncthreads();
      {
        float4 z = make_float4(0.f, 0.f, 0.f, 0.f);
        int ra = i0 + srow, rb = j0 + srow;
        float4 va = (ra < NCLS) ? *(const float4*)(spn + (size_t)ra * DIM + k0 + skq) : z;
        float4 vb = (rb < NCLS) ? *(const float4*)(spn + (size_t)rb * DIM + k0 + skq) : z;
        float4 wa = (ra < NCLS) ? *(const float4*)(tpn + (size_t)ra * DIM + k0 + skq) : z;
        float4 wb = (rb < NCLS) ? *(const float4*)(tpn + (size_t)rb * DIM + k0 + skq) : z;
        Sa[skq+0][srow]=va.x; Sa[skq+1][srow]=va.y; Sa[skq+2][srow]=va.z; Sa[skq+3][srow]=va.w;
        Sb[skq+0][srow]=vb.x; Sb[skq+1][srow]=vb.y; Sb[skq+2][srow]=vb.z; Sb[skq+3][srow]=vb.w;
        Ta[skq+0][srow]=wa.x; Ta[skq+1][srow]=wa.y; Ta[skq+2][srow]=wa.z; Ta[skq+3][srow]=wa.w;
        Tb[skq+0][srow]=wb.x; Tb[skq+1][srow]=wb.y; Tb[skq+2][srow]=wb.z; Tb[skq+3][srow]=wb.w;
      }
      __syncthreads();
      #pragma unroll
      for (int k = 0; k < 16; k++) {
        float a[4], b[4], c[4], d[4];
        *(float4*)a = *(const float4*)&Sa[k][ty * 4];
        *(float4*)b = *(const float4*)&Sb[k][tx * 4];
        *(float4*)c = *(const float4*)&Ta[k][ty * 4];
        *(float4*)d = *(const float4*)&Tb[k][tx * 4];
        #pragma unroll
        for (int ii = 0; ii < 4; ii++)
          #pragma unroll
          for (int jj = 0; jj < 4; jj++) {
            cs[ii][jj] = fmaf(a[ii], b[jj], cs[ii][jj]);
            cg[ii][jj] = fmaf(c[ii], d[jj], cg[ii][jj]);
          }
      }
    }
    float d2 = 0.f;
    #pragma unroll
    for (int ii = 0; ii < 4; ii++) {
      int gi = i0 + ty * 4 + ii;
      if (gi < NCLS) {
        #pragma unroll
        for (int jj = 0; jj < 4; jj++) {
          int gj = j0 + tx * 4 + jj;
          if (gj < NCLS) {
            out_struct[(size_t)gi * NCLS + gj] = cs[ii][jj];
            float df = cs[ii][jj] - cg[ii][jj];
            d2 += df * df;
          }
        }
      }
    }
    red[t] = d2;
    __syncthreads();
    for (int o = 128; o > 0; o >>= 1) { if (t < o) red[t] += red[t + o]; __syncthreads(); }
    if (t == 0) atomicAdd(acc, red[0]);
    return;
  }

  // ================= contrast path (no barriers; wave-private LDS) ============
  const int cbid = bid - 256;
  if (cbid >= cblocks) return;
  const int lane = t & 63;
  const int w = t >> 6;
  const int lx = lane & 15, lg = lane >> 4;
  const int row0 = cbid * 128 + w * 32;
  const float4 z4 = make_float4(0.f, 0.f, 0.f, 0.f);
  const unsigned char* bbase = pbf8 + (lg << 8) + (lx << 4);
  float* Aw = (float*)lds_raw + (size_t)w * (32 * 68);  // wave-private 8.7KB

  i64 af[2][8];            // 32 rows/wave, raw feats in e4m3
  float sclF[2][4];        // (1/(T*ln2))/||f|| per owned row
  float sSt[2][4];
  int lbR[2];              // label of this lane's owned row (per rf)

  // ---- coalesced prologue: 4 chunks of {stage 32rows x 64cols -> ds_read} ----
  float n2a[2] = {0.f, 0.f};
  for (int kc = 0; kc < 4; kc++) {
    #pragma unroll
    for (int i = 0; i < 8; i++) {
      const int f = i * 64 + lane;        // float4 index in [0,512)
      const int row = f >> 4;             // 0..31
      const int c4 = f & 15;              // 0..15
      const int gr = row0 + row;
      float4 v = (gr < N) ? *(const float4*)(feats + (size_t)gr * DIM + kc * 64 + c4 * 4) : z4;
      *(float4*)&Aw[row * 68 + c4 * 4] = v;
    }
    // compiler inserts lgkmcnt before dependent reads (wave-private region)
    #pragma unroll
    for (int rf = 0; rf < 2; rf++) {
      const int row = rf * 16 + lx;
      #pragma unroll
      for (int kk = 0; kk < 2; kk++) {
        float4 x = *(const float4*)&Aw[row * 68 + kk * 32 + lg * 8];
        float4 y = *(const float4*)&Aw[row * 68 + kk * 32 + lg * 8 + 4];
        n2a[rf] += x.x*x.x + x.y*x.y + x.z*x.z + x.w*x.w
                 + y.x*y.x + y.y*y.y + y.z*y.z + y.w*y.w;
        unsigned w0 = CVTPK(x.x, x.y, 0u, false);
        w0 = CVTPK(x.z, x.w, w0, true);
        unsigned w1 = CVTPK(y.x, y.y, 0u, false);
        w1 = CVTPK(y.z, y.w, w1, true);
        af[rf][kc * 2 + kk] = (i64)(((u64)w1 << 32) | (u64)w0);
      }
    }
  }
  #pragma unroll
  for (int rf = 0; rf < 2; rf++) {
    const int r = row0 + rf * 16 + lx;
    lbR[rf] = (r < N) ? labels[r] : 0;
    float n2 = n2a[rf];
    n2 += __shfl_xor(n2, 16);
    n2 += __shfl_xor(n2, 32);
    const float sw = SCLF / fmaxf(sqrtf(n2), 1e-12f);
    #pragma unroll
    for (int reg = 0; reg < 4; reg++) {
      sclF[rf][reg] = __shfl(sw, (lg << 2) | reg);
      sSt[rf][reg] = 0.f;
    }
  }

  int4 bA[4], bB[4];

  #define LOADB(dst_, cf_)                                                      \
    {                                                                           \
      const int4* gp = (const int4*)(bbase + ((size_t)(cf_) << 12));            \
      _Pragma("unroll")                                                         \
      for (int q = 0; q < 4; q++) dst_[q] = gp[q << 6];                         \
    }

  #define COMPUTE(buf_)                                                         \
    {                                                                           \
      f32x4 d0 = {0.f, 0.f, 0.f, 0.f};                                          \
      f32x4 d1 = {0.f, 0.f, 0.f, 0.f};                                          \
      __builtin_amdgcn_s_setprio(1);                                            \
      _Pragma("unroll")                                                         \
      for (int q = 0; q < 4; q++) {                                             \
        i64 e0 = ((const i64*)&buf_[q])[0];                                     \
        i64 e1 = ((const i64*)&buf_[q])[1];                                     \
        d0 = __builtin_amdgcn_mfma_f32_16x16x32_fp8_fp8(af[0][2*q],   e0, d0, 0, 0, 0); \
        d1 = __builtin_amdgcn_mfma_f32_16x16x32_fp8_fp8(af[1][2*q],   e0, d1, 0, 0, 0); \
        d0 = __builtin_amdgcn_mfma_f32_16x16x32_fp8_fp8(af[0][2*q+1], e1, d0, 0, 0, 0); \
        d1 = __builtin_amdgcn_mfma_f32_16x16x32_fp8_fp8(af[1][2*q+1], e1, d1, 0, 0, 0); \
      }                                                                         \
      __builtin_amdgcn_s_setprio(0);                                            \
      _Pragma("unroll")                                                         \
      for (int reg = 0; reg < 4; reg++) {                                       \
        sSt[0][reg] += fexp2(fmaf(d0[reg], sclF[0][reg], -CP));                 \
        sSt[1][reg] += fexp2(fmaf(d1[reg], sclF[1][reg], -CP));                 \
      }                                                                         \
    }

  LOADB(bA, 0);
  for (int cf = 0; cf < NT16; cf += 2) {
    LOADB(bB, cf + 1);
    COMPUTE(bA);
    if (cf + 2 < NT16) LOADB(bA, cf + 2);
    COMPUTE(bB);
  }

  // ---- label logits via MFMA diagonal: B-col j = proto of row j's label ----
  float dvalS[2];
  #pragma unroll
  for (int rf = 0; rf < 2; rf++) {
    const int lb = lbR[rf];
    const unsigned char* gB = pbf8 + ((size_t)(lb >> 4) << 12) + (lg << 8)
                            + ((size_t)(lb & 15) << 4);
    f32x4 dL = {0.f, 0.f, 0.f, 0.f};
    #pragma unroll
    for (int q = 0; q < 4; q++) {
      int4 bg = *(const int4*)(gB + (q << 10));
      i64 e0 = ((const i64*)&bg)[0];
      i64 e1 = ((const i64*)&bg)[1];
      dL = __builtin_amdgcn_mfma_f32_16x16x32_fp8_fp8(af[rf][2*q],   e0, dL, 0, 0, 0);
      dL = __builtin_amdgcn_mfma_f32_16x16x32_fp8_fp8(af[rf][2*q+1], e1, dL, 0, 0, 0);
    }
    const int sel = lx & 3;   // diag D[j][j]: at lane ((j>>2)<<4)|j, reg j&3
    dvalS[rf] = (sel == 0) ? dL[0] : (sel == 1) ? dL[1] : (sel == 2) ? dL[2] : dL[3];
  }

  float wl = 0.f;
  #pragma unroll
  for (int rf = 0; rf < 2; rf++)
    #pragma unroll
    for (int reg = 0; reg < 4; reg++) {
      float s = sSt[rf][reg];
      #pragma unroll
      for (int o = 1; o < 16; o <<= 1) s += __shfl_xor(s, o);
      const int j = (lg << 2) + reg;
      const float lbraw = __shfl(dvalS[rf], ((j >> 2) << 4) | j);
      const int row = row0 + rf * 16 + j;
      if (lx == 0 && row < N)
        wl += logf(s - PADC) + CPLN2 - lbraw * sclF[rf][reg] * LN2;
    }

  #pragma unroll
  for (int o = 1; o < 64; o <<= 1) wl += __shfl_xor(wl, o);
  if (lane == 0) atomicAdd(accp + (cbid & 63), wl);
}

// ---------------- K4: scalars ---------------------------------------------------
__global__ void final_kernel(const float* __restrict__ acc,
                             const float* __restrict__ accp,
                             float* __restrict__ out, int N) {
  float c = 0.f;
  for (int i = 0; i < 64; i++) c += accp[i];
  out[0] = acc[0] * (1.0f / (float)(NCLS * NCLS));
  out[1] = c / (float)N;
}

extern "C" void kernel_launch(void* const* d_in, const int* in_sizes, int n_in,
                              void* d_out, int out_size, void* d_ws, size_t ws_size,
                              hipStream_t stream) {
  const float* src_feats  = (const float*)d_in[0];
  const int*   src_labels = (const int*)d_in[1];
  const float* tgt_feats  = (const float*)d_in[2];
  const int*   tgt_labels = (const int*)d_in[3];
  const int N = in_sizes[0] / DIM;

  // ws layout (floats) — zeroed region is contiguous [0, 2080):
  // [0,16)             acc: [0]=struct sq-sum
  // [16,2016)          gcnt: 2000 ints
  // [2016,2080)        accp: 64 contrast partial bins
  // [2080,258080)      src_pn
  // [258080,514080)    tgt_pn
  // [514080,579616)    pbf8: 64 tiles x 4096 bytes (fp8 e4m3)
  float* ws = (float*)d_ws;
  float* acc    = ws;
  int*   gcnt   = (int*)(ws + 16);
  float* accp   = ws + 2016;
  float* src_pn = ws + 2080;
  float* tgt_pn = ws + 258080;
  unsigned char* pbf8 = (unsigned char*)(ws + 514080);

  float* out_f      = (float*)d_out;
  float* out_protos = out_f + 2;
  float* out_struct = out_f + 2 + NCLS * DIM;
  // glist borrows the out_struct region (1M ints); fused struct path overwrites later
  int* glist = (int*)out_struct;

  hipMemsetAsync(ws, 0, 2080 * sizeof(float), stream);        // acc + gcnt + accp
  hipMemsetAsync(pbf8 + 62 * 4096, 0, 2 * 4096, stream);      // pad tiles 62,63

  int sblocks = (2 * N + 255) / 256;
  scatter_kernel<<<sblocks, 256, 0, stream>>>(src_labels, tgt_labels, N, gcnt, glist);

  proto_kernel<<<2 * NCLS, 256, 0, stream>>>(src_feats, tgt_feats, gcnt, glist,
                                             out_protos, src_pn, tgt_pn, pbf8);

  int cblocks = (N + 127) / 128;
  fused_kernel<<<256 + cblocks, 256, 0, stream>>>(
      src_feats, src_labels, pbf8, accp, src_pn, tgt_pn, out_struct, acc, N, cblocks);

  final_kernel<<<1, 1, 0, stream>>>(acc, accp, out_f, N);
}